// Round 15
// baseline (56544.342 us; speedup 1.0000x reference)
//
#include <hip/hip_runtime.h>
#include <math.h>

// ResRnn on MI355X — round 15: HALVE per-CU L2 weight traffic.
// Thread remap (ks:32,bg:4,ng:4) -> (ks:64,bh:2,ng:4): each Wcd double2 fetched
// by 2 threads instead of 4 (512->256 KB/CU/step of L2 requests). Everything
// else is the proven r6 skeleton: 256 blocks x 512 threads, 1 block/CU via
// 144 KB LDS, atomic v-exchange, full-grid 16-leaf release-fence barrier.
// k-reduction: 3-step shfl_xor butterfly (64->8 slices) + 8-slice LDS reduce.
// fp64 reorder safe (r4/r5 evidence). Expect absmax ~= 4.195923e+33.
// u_t = v_{t-1} @ Wc^T + bias + x_t @ W1p^T ; v_t = u + bo*sin(u*inw)

#define WDIM 1024
#define SEQ_N 2048
#define NB 256
#define LDS_N 147456   // 16*512*16 (v-tile) + 256*8*8 (red)

__device__ __forceinline__ double gload(const double* p) {
  unsigned long long v = __hip_atomic_load((const unsigned long long*)p,
                                           __ATOMIC_RELAXED, __HIP_MEMORY_SCOPE_AGENT);
  return __builtin_bit_cast(double, v);
}
__device__ __forceinline__ void gstore(double* p, double d) {
  __hip_atomic_store((unsigned long long*)p, __builtin_bit_cast(unsigned long long, d),
                     __ATOMIC_RELAXED, __HIP_MEMORY_SCOPE_AGENT);
}

// full-grid tree barrier, r6 fence semantics (release fence, relaxed flags)
__device__ __forceinline__ void gbar(unsigned* bar, unsigned target, int leaf) {
  __syncthreads();
  if (threadIdx.x == 0) {
    __builtin_amdgcn_fence(__ATOMIC_RELEASE, "agent");
    unsigned old = __hip_atomic_fetch_add(&bar[32 + leaf * 16], 1u, __ATOMIC_RELAXED,
                                          __HIP_MEMORY_SCOPE_AGENT);
    if (old + 1u == target * 16u) {
      unsigned r = __hip_atomic_fetch_add(&bar[16], 1u, __ATOMIC_RELAXED,
                                          __HIP_MEMORY_SCOPE_AGENT);
      if (r + 1u == target * 16u)
        __hip_atomic_store(&bar[0], target, __ATOMIC_RELAXED, __HIP_MEMORY_SCOPE_AGENT);
    }
    while (__hip_atomic_load(&bar[0], __ATOMIC_RELAXED, __HIP_MEMORY_SCOPE_AGENT) < target)
      __builtin_amdgcn_s_sleep(2);
  }
  __syncthreads();
}

// ---- precompute: Wcd[n][k] = sum_j W1[n][j]*W2[j][k] (fp64) ----
__global__ __launch_bounds__(256) void k_gemm_wt(const float* __restrict__ A,
                                                 const float* __restrict__ B,
                                                 double* __restrict__ Wcd) {
  __shared__ float As[32][68];
  __shared__ float Bs[32][68];
  const int tid = threadIdx.x;
  const int tx = tid & 15, ty = tid >> 4;
  const int bx = blockIdx.x, by = blockIdx.y;
  double acc[4][4] = {};
  for (int j0 = 0; j0 < WDIM; j0 += 32) {
    for (int l = tid; l < 64 * 32; l += 256) {
      int r = l >> 5, c = l & 31;
      As[c][r] = A[(by * 64 + r) * WDIM + j0 + c];
    }
    for (int l = tid; l < 32 * 64; l += 256) {
      int r = l >> 6, c = l & 63;
      Bs[r][c] = B[(j0 + r) * WDIM + bx * 64 + c];
    }
    __syncthreads();
#pragma unroll 8
    for (int kk = 0; kk < 32; ++kk) {
      float a[4], bb[4];
      *(float4*)a  = *(const float4*)&As[kk][ty * 4];
      *(float4*)bb = *(const float4*)&Bs[kk][tx * 4];
#pragma unroll
      for (int i = 0; i < 4; ++i)
#pragma unroll
        for (int j = 0; j < 4; ++j) acc[i][j] += (double)a[i] * (double)bb[j];
    }
    __syncthreads();
  }
#pragma unroll
  for (int i = 0; i < 4; ++i)
#pragma unroll
    for (int j = 0; j < 4; ++j)
      Wcd[(size_t)(by * 64 + ty * 4 + i) * WDIM + bx * 64 + tx * 4 + j] = acc[i][j];
}

// ---- precompute: fp64 biases; zero barrier region ----
__global__ __launch_bounds__(256) void k_bias(const float* __restrict__ W1,
                                              const float* __restrict__ b1,
                                              const float* __restrict__ b2,
                                              const float* __restrict__ s0,
                                              double* __restrict__ b1c,
                                              double* __restrict__ c0, unsigned* bar) {
  if (blockIdx.x < 4) bar[blockIdx.x * 256 + threadIdx.x] = 0u;
  int wave = threadIdx.x >> 6;
  int lane = threadIdx.x & 63;
  int n = blockIdx.x * 4 + wave;
  const float* row = W1 + (size_t)n * WDIM;
  double a1 = 0.0, a2 = 0.0;
  for (int k = lane; k < WDIM; k += 64) {
    double w = (double)row[k];
    a1 += (double)b2[k] * w;
    a2 += (double)s0[k] * w;
  }
#pragma unroll
  for (int off = 32; off; off >>= 1) {
    a1 += __shfl_down(a1, off, 64);
    a2 += __shfl_down(a2, off, 64);
  }
  if (lane == 0) { b1c[n] = (double)b1[n] + a1; c0[n] = (double)b1[n] + a2; }
}

// ---- main: 256 blocks x 512 threads; thread = (ks:64, bh:2, ng:4) ----
// block (g=blk>>6, nt=blk&63): 16 b-rows x 16 n-cols.
// thread: 8 b-rows (bh*8+r), 4 n-rows (ng*4+jn), k-slice c2 = i*64+ks (i<8).
// Each weight double2 read by exactly 2 threads (bh pair) -> 256 KB/CU/step L2.
__global__ __launch_bounds__(512, 2) void k_main(
    const float* __restrict__ x, const double* __restrict__ Wcd,
    const float* __restrict__ W1, const double* __restrict__ b1c,
    const double* __restrict__ c0, const float* __restrict__ W2,
    const float* __restrict__ b2, const float* __restrict__ bend,
    const float* __restrict__ inner, const float* __restrict__ outer,
    double* vA, double* vB, float* __restrict__ out, unsigned* bar) {
  extern __shared__ double2 tile[];            // [16*512] double2 (128 KB)
  double* red = (double*)(tile + 8192);        // [256*8] double (16 KB)
  const int tid = threadIdx.x;
  const int ks = tid & 63;
  const int bh = (tid >> 6) & 1;
  const int ng = tid >> 7;
  const int nt = blockIdx.x & 63, g = blockIdx.x >> 6;
  const int leaf = blockIdx.x >> 4;

  if (tid < 256) vA[blockIdx.x * 256 + tid] = 0.0;  // flushed by first gbar fence

  const double* wrow[4];
  const float* w1row[4];
  const float* w2row[4];
#pragma unroll
  for (int jn = 0; jn < 4; ++jn) {
    int n = nt * 16 + ng * 4 + jn;
    wrow[jn]  = Wcd + (size_t)n * WDIM;
    w1row[jn] = W1 + (size_t)n * WDIM;
    w2row[jn] = W2 + (size_t)n * WDIM;
  }

  const int n_red = nt * 16 + (tid & 15);
  const int b_red = g * 16 + ((tid >> 4) & 15);
  const double bo   = (double)bend[n_red] * (double)outer[n_red];
  const double inw  = (double)inner[n_red];
  const double b1cr = b1c[n_red];
  const double c0r  = c0[n_red];

  unsigned gent = 0;
  double* vin = vA;
  double* vout = vB;
  gbar(bar, ++gent, leaf);

  for (int t = 0; t < SEQ_N; ++t) {
    // ---- x & W1 fragment loads (L2; issue before v to overlap) ----
    float2 xv[8][2], wv1[4][2];
#pragma unroll
    for (int i = 0; i < 2; ++i) {
      int c2f = i * 64 + ks;   // float2 col < 128
#pragma unroll
      for (int r = 0; r < 8; ++r)
        xv[r][i] = ((const float2*)(x + ((size_t)t * 64 + g * 16 + bh * 8 + r) * 256))[c2f];
#pragma unroll
      for (int jn = 0; jn < 4; ++jn)
        wv1[jn][i] = ((const float2*)w1row[jn])[c2f];
    }
    // ---- batched atomic v loads (IF$) ----
    double va[16], vb[16];
    {
      const double* srcb = vin + (size_t)(g * 16) * WDIM + tid * 2;
#pragma unroll
      for (int j = 0; j < 16; ++j) {
        va[j] = gload(srcb + (size_t)j * WDIM);
        vb[j] = gload(srcb + (size_t)j * WDIM + 1);
      }
    }
    // ---- x-injection FMA (overlaps v latency) ----
    double accx[8][4], accy[8][4];
#pragma unroll
    for (int r = 0; r < 8; ++r)
#pragma unroll
      for (int jn = 0; jn < 4; ++jn) { accx[r][jn] = 0.0; accy[r][jn] = 0.0; }
#pragma unroll
    for (int i = 0; i < 2; ++i)
#pragma unroll
      for (int jn = 0; jn < 4; ++jn) {
        double wx = (double)wv1[jn][i].x, wy = (double)wv1[jn][i].y;
#pragma unroll
        for (int r = 0; r < 8; ++r) {
          accx[r][jn] += (double)xv[r][i].x * wx;
          accy[r][jn] += (double)xv[r][i].y * wy;
        }
      }
    // ---- stage full v-tile (row j uniform, col tid: conflict-free) ----
#pragma unroll
    for (int j = 0; j < 16; ++j)
      tile[j * 512 + tid] = make_double2(va[j], vb[j]);
    __syncthreads();  // S1

    // ---- weight FMA: c2 = i*64+ks, i<8; each w double2 read by 2 threads ----
#pragma unroll 2
    for (int i = 0; i < 8; ++i) {
      int c2 = i * 64 + ks;
      double2 vv[8];
#pragma unroll
      for (int r = 0; r < 8; ++r)
        vv[r] = tile[(bh * 8 + r) * 512 + c2];
#pragma unroll
      for (int jn = 0; jn < 4; ++jn) {
        double2 w = ((const double2*)wrow[jn])[c2];
#pragma unroll
        for (int r = 0; r < 8; ++r) {
          accx[r][jn] += vv[r].x * w.x;
          accy[r][jn] += vv[r].y * w.y;
        }
      }
    }

    // ---- butterfly reduce 64 k-slices -> 8, store to red ----
#pragma unroll
    for (int r = 0; r < 8; ++r)
#pragma unroll
      for (int jn = 0; jn < 4; ++jn) {
        double p = accx[r][jn] + accy[r][jn];
        p += __shfl_xor(p, 32, 64);
        p += __shfl_xor(p, 16, 64);
        p += __shfl_xor(p, 8, 64);
        if (ks < 8) {
          int o = (bh * 8 + r) * 16 + ng * 4 + jn;
          red[o * 8 + (ks ^ (o & 7))] = p;
        }
      }
    __syncthreads();  // S2

    // ---- final reduce (tid<256), activation, atomic store v_t ----
    if (tid < 256) {
      double s = 0.0;
      const int oc = tid & 7;
#pragma unroll
      for (int slc = 0; slc < 8; ++slc)
        s += red[tid * 8 + (slc ^ oc)];
      double u = s + (t == 0 ? c0r : b1cr);
      double gv = u + bo * sin(u * inw);
      gstore(&vout[(size_t)b_red * WDIM + n_red], gv);
    }
    gbar(bar, ++gent, leaf);
    double* tmp = vin; vin = vout; vout = tmp;
  }

  // ---------------- epilogue: stream = v_2047 @ W2^T + b2 ----------------
  {
    double va[16], vb[16];
    {
      const double* srcb = vin + (size_t)(g * 16) * WDIM + tid * 2;
#pragma unroll
      for (int j = 0; j < 16; ++j) {
        va[j] = gload(srcb + (size_t)j * WDIM);
        vb[j] = gload(srcb + (size_t)j * WDIM + 1);
      }
    }
#pragma unroll
    for (int j = 0; j < 16; ++j)
      tile[j * 512 + tid] = make_double2(va[j], vb[j]);
    __syncthreads();

    double accx[8][4], accy[8][4];
#pragma unroll
    for (int r = 0; r < 8; ++r)
#pragma unroll
      for (int jn = 0; jn < 4; ++jn) { accx[r][jn] = 0.0; accy[r][jn] = 0.0; }
#pragma unroll 2
    for (int i = 0; i < 8; ++i) {
      int c2 = i * 64 + ks;
      double2 vv[8];
#pragma unroll
      for (int r = 0; r < 8; ++r)
        vv[r] = tile[(bh * 8 + r) * 512 + c2];
#pragma unroll
      for (int jn = 0; jn < 4; ++jn) {
        float2 wf = ((const float2*)w2row[jn])[c2];
        double wx = (double)wf.x, wy = (double)wf.y;
#pragma unroll
        for (int r = 0; r < 8; ++r) {
          accx[r][jn] += vv[r].x * wx;
          accy[r][jn] += vv[r].y * wy;
        }
      }
    }
#pragma unroll
    for (int r = 0; r < 8; ++r)
#pragma unroll
      for (int jn = 0; jn < 4; ++jn) {
        double p = accx[r][jn] + accy[r][jn];
        p += __shfl_xor(p, 32, 64);
        p += __shfl_xor(p, 16, 64);
        p += __shfl_xor(p, 8, 64);
        if (ks < 8) {
          int o = (bh * 8 + r) * 16 + ng * 4 + jn;
          red[o * 8 + (ks ^ (o & 7))] = p;
        }
      }
    __syncthreads();
    if (tid < 256) {
      double s = 0.0;
      const int oc = tid & 7;
#pragma unroll
      for (int slc = 0; slc < 8; ++slc)
        s += red[tid * 8 + (slc ^ oc)];
      double sv = s + (double)b2[n_red];
      out[4096 + (size_t)b_red * WDIM + n_red] = (float)sv;
      if (n_red < 64) out[(size_t)b_red * 64 + n_red] = (float)sv;
    }
  }
}

extern "C" void kernel_launch(void* const* d_in, const int* in_sizes, int n_in,
                              void* d_out, int out_size, void* d_ws, size_t ws_size,
                              hipStream_t stream) {
  const float* x    = (const float*)d_in[0];
  const float* s0   = (const float*)d_in[1];
  const float* W1   = (const float*)d_in[2];
  const float* b1   = (const float*)d_in[3];
  const float* W2   = (const float*)d_in[4];
  const float* b2   = (const float*)d_in[5];
  const float* bend = (const float*)d_in[6];
  const float* inner= (const float*)d_in[7];
  const float* outer= (const float*)d_in[8];
  double* ws = (double*)d_ws;

  double* Wcd = ws;
  double* b1c = ws + 1048576;
  double* c0  = ws + 1049600;
  double* vA  = ws + 1050624;
  double* vB  = ws + 1116160;
  unsigned* bar = (unsigned*)(ws + 1181696);
  float* out = (float*)d_out;

  k_gemm_wt<<<dim3(16, 16), 256, 0, stream>>>(W1, W2, Wcd);
  k_bias<<<256, 256, 0, stream>>>(W1, b1, b2, s0, b1c, c0, bar);

  static bool attr_done = false;
  if (!attr_done) {
    hipFuncSetAttribute((const void*)k_main, hipFuncAttributeMaxDynamicSharedMemorySize, LDS_N);
    attr_done = true;
  }

  void* args[] = { (void*)&x, (void*)&Wcd, (void*)&W1, (void*)&b1c, (void*)&c0,
                   (void*)&W2, (void*)&b2, (void*)&bend, (void*)&inner, (void*)&outer,
                   (void*)&vA, (void*)&vB, (void*)&out, (void*)&bar };
  // 256 blocks, 1 block/CU by LDS (144 KB) -> co-resident; coop preferred
  if (hipLaunchCooperativeKernel((void*)k_main, dim3(NB), dim3(512), args,
                                 LDS_N, stream) != hipSuccess) {
    k_main<<<dim3(NB), dim3(512), LDS_N, stream>>>(
        x, Wcd, W1, b1c, c0, W2, b2, bend, inner, outer, vA, vB, out, bar);
  }
}

// Round 16
// 40703.317 us; speedup vs baseline: 1.3892x; 1.3892x over previous
//
#include <hip/hip_runtime.h>
#include <math.h>

// ResRnn on MI355X — round 16: XCD-local v-staging (8x cut in IF$ traffic).
// Theory: all variants stall ~15 us/step on the 32 MB/step v-broadcast through
// the Infinity Cache (64x read amplification; only IF$ serves cross-XCD data).
// Fix: blocks discover their REAL XCD (s_getreg HW_REG_XCC_ID), form (xcd,group)
// cohorts, stage the group's v-tile ONCE per XCD from IF$ into XCD-local scratch
// (plain dirty-L2 stores; fence-free barriers never flush it), sync via per-cohort
// IF$ flag, buffer_inv (L1-only), consume from local L2. 32->4.5 MB/step IF$.
// Summation order identical to r6 -> absmax canary 4.195923e+33.
// Fallback (ws too small): r6-exact kernel.
// u_t = v_{t-1} @ Wc^T + bias + x_t @ W1p^T ; v_t = u + bo*sin(u*inw)

#define WDIM 1024
#define SEQ_N 2048
#define NB 256
#define LDS_BYTES 163840

__device__ __forceinline__ double gload(const double* p) {
  unsigned long long v = __hip_atomic_load((const unsigned long long*)p,
                                           __ATOMIC_RELAXED, __HIP_MEMORY_SCOPE_AGENT);
  return __builtin_bit_cast(double, v);
}
__device__ __forceinline__ void gstore(double* p, double d) {
  __hip_atomic_store((unsigned long long*)p, __builtin_bit_cast(unsigned long long, d),
                     __ATOMIC_RELAXED, __HIP_MEMORY_SCOPE_AGENT);
}

// fence-free full-grid tree barrier (r8/r9-proven): per-wave vmcnt drain + relaxed
// IF$ flag atomics. No wbl2/inv -> XCD-local dirty scratch lines survive.
__device__ __forceinline__ void gbarNF(unsigned* bar, unsigned target, int leaf) {
  asm volatile("s_waitcnt vmcnt(0)" ::: "memory");
  __syncthreads();
  if (threadIdx.x == 0) {
    unsigned old = __hip_atomic_fetch_add(&bar[32 + leaf * 16], 1u, __ATOMIC_RELAXED,
                                          __HIP_MEMORY_SCOPE_AGENT);
    if (old + 1u == target * 16u) {
      unsigned r = __hip_atomic_fetch_add(&bar[16], 1u, __ATOMIC_RELAXED,
                                          __HIP_MEMORY_SCOPE_AGENT);
      if (r + 1u == target * 16u)
        __hip_atomic_store(&bar[0], target, __ATOMIC_RELAXED, __HIP_MEMORY_SCOPE_AGENT);
    }
    while (__hip_atomic_load(&bar[0], __ATOMIC_RELAXED, __HIP_MEMORY_SCOPE_AGENT) < target)
      __builtin_amdgcn_s_sleep(2);
  }
  __syncthreads();
}

// r6-exact barrier (release fence) for the legacy fallback kernel
__device__ __forceinline__ void gbarF(unsigned* bar, unsigned target, int leaf) {
  __syncthreads();
  if (threadIdx.x == 0) {
    __builtin_amdgcn_fence(__ATOMIC_RELEASE, "agent");
    unsigned old = __hip_atomic_fetch_add(&bar[32 + leaf * 16], 1u, __ATOMIC_RELAXED,
                                          __HIP_MEMORY_SCOPE_AGENT);
    if (old + 1u == target * 16u) {
      unsigned r = __hip_atomic_fetch_add(&bar[16], 1u, __ATOMIC_RELAXED,
                                          __HIP_MEMORY_SCOPE_AGENT);
      if (r + 1u == target * 16u)
        __hip_atomic_store(&bar[0], target, __ATOMIC_RELAXED, __HIP_MEMORY_SCOPE_AGENT);
    }
    while (__hip_atomic_load(&bar[0], __ATOMIC_RELAXED, __HIP_MEMORY_SCOPE_AGENT) < target)
      __builtin_amdgcn_s_sleep(2);
  }
  __syncthreads();
}

// ---- precompute: Wcd[n][k] = sum_j W1[n][j]*W2[j][k] (fp64) ----
__global__ __launch_bounds__(256) void k_gemm_wt(const float* __restrict__ A,
                                                 const float* __restrict__ B,
                                                 double* __restrict__ Wcd) {
  __shared__ float As[32][68];
  __shared__ float Bs[32][68];
  const int tid = threadIdx.x;
  const int tx = tid & 15, ty = tid >> 4;
  const int bx = blockIdx.x, by = blockIdx.y;
  double acc[4][4] = {};
  for (int j0 = 0; j0 < WDIM; j0 += 32) {
    for (int l = tid; l < 64 * 32; l += 256) {
      int r = l >> 5, c = l & 31;
      As[c][r] = A[(by * 64 + r) * WDIM + j0 + c];
    }
    for (int l = tid; l < 32 * 64; l += 256) {
      int r = l >> 6, c = l & 63;
      Bs[r][c] = B[(j0 + r) * WDIM + bx * 64 + c];
    }
    __syncthreads();
#pragma unroll 8
    for (int kk = 0; kk < 32; ++kk) {
      float a[4], bb[4];
      *(float4*)a  = *(const float4*)&As[kk][ty * 4];
      *(float4*)bb = *(const float4*)&Bs[kk][tx * 4];
#pragma unroll
      for (int i = 0; i < 4; ++i)
#pragma unroll
        for (int j = 0; j < 4; ++j) acc[i][j] += (double)a[i] * (double)bb[j];
    }
    __syncthreads();
  }
#pragma unroll
  for (int i = 0; i < 4; ++i)
#pragma unroll
    for (int j = 0; j < 4; ++j)
      Wcd[(size_t)(by * 64 + ty * 4 + i) * WDIM + bx * 64 + tx * 4 + j] = acc[i][j];
}

// ---- precompute: fp64 biases; zero barrier/flag region (4096 dwords) ----
__global__ __launch_bounds__(256) void k_bias(const float* __restrict__ W1,
                                              const float* __restrict__ b1,
                                              const float* __restrict__ b2,
                                              const float* __restrict__ s0,
                                              double* __restrict__ b1c,
                                              double* __restrict__ c0, unsigned* bar) {
  if (blockIdx.x < 16) bar[blockIdx.x * 256 + threadIdx.x] = 0u;
  int wave = threadIdx.x >> 6;
  int lane = threadIdx.x & 63;
  int n = blockIdx.x * 4 + wave;
  const float* row = W1 + (size_t)n * WDIM;
  double a1 = 0.0, a2 = 0.0;
  for (int k = lane; k < WDIM; k += 64) {
    double w = (double)row[k];
    a1 += (double)b2[k] * w;
    a2 += (double)s0[k] * w;
  }
#pragma unroll
  for (int off = 32; off; off >>= 1) {
    a1 += __shfl_down(a1, off, 64);
    a2 += __shfl_down(a2, off, 64);
  }
  if (lane == 0) { b1c[n] = (double)b1[n] + a1; c0[n] = (double)b1[n] + a2; }
}

// ============ main with XCD-local staging (256 x 512, 160 KB LDS) ============
// bar layout (dwords): [0..511] grid tree; [512 + pair*16] cohort flags (pair<32);
// [1536 + pair] cohort registration counters.
// scratch layout (doubles): [pair][slot<2][16*1024].
__global__ __launch_bounds__(512, 2) void k_mainX(
    const float* __restrict__ x, const double* __restrict__ Wcd,
    const float* __restrict__ W1, const double* __restrict__ b1c,
    const double* __restrict__ c0, const float* __restrict__ W2,
    const float* __restrict__ b2, const float* __restrict__ bend,
    const float* __restrict__ inner, const float* __restrict__ outer,
    double* vA, double* vB, double* scratch, float* __restrict__ out,
    unsigned* bar) {
  extern __shared__ double2 tile[];            // [16*512] double2 (128 KB)
  double* red = (double*)(tile + 8192);        // [256*16] double (32 KB)
  unsigned* meta = (unsigned*)red;             // init-time broadcast (pre-loop only)
  const int tid = threadIdx.x;
  const int ks = tid & 31;
  const int bg = (tid >> 5) & 3;
  const int ng = (tid >> 7) & 3;
  const int nt = blockIdx.x & 63, g = blockIdx.x >> 6;
  const int leaf = blockIdx.x >> 4;

  // ---- cohort registration (real XCD via s_getreg) ----
  if (tid == 0) {
    unsigned xcc;
    asm volatile("s_getreg_b32 %0, hwreg(HW_REG_XCC_ID)" : "=s"(xcc));
    unsigned pr = (xcc & 7u) * 4u + (unsigned)g;
    unsigned rk = __hip_atomic_fetch_add(&bar[1536 + pr], 1u, __ATOMIC_RELAXED,
                                         __HIP_MEMORY_SCOPE_AGENT);
    meta[0] = pr; meta[1] = rk;
  }
  __syncthreads();
  const unsigned pair = meta[0];
  const unsigned rank = meta[1];
  unsigned* xflag = bar + 512 + pair * 16;
  double* scr0 = scratch + (size_t)pair * 2 * 16384;

  if (tid < 256) gstore(&vA[blockIdx.x * 256 + tid], 0.0);  // zero v_{-1} at IF$

  const double* wrow[4];
  const float* w1row[4];
  const float* w2row[4];
#pragma unroll
  for (int jn = 0; jn < 4; ++jn) {
    int n = nt * 16 + ng * 4 + jn;
    wrow[jn]  = Wcd + (size_t)n * WDIM;
    w1row[jn] = W1 + (size_t)n * WDIM;
    w2row[jn] = W2 + (size_t)n * WDIM;
  }

  const int n_red = nt * 16 + (tid & 15);
  const int b_red = g * 16 + ((tid >> 4) & 15);
  const double bo   = (double)bend[n_red] * (double)outer[n_red];
  const double inw  = (double)inner[n_red];
  const double b1cr = b1c[n_red];
  const double c0r  = c0[n_red];
  const int oswz = (ng * 4) & 15;

  unsigned gent = 0;
  double* vin = vA;
  double* vout = vB;
  gbarNF(bar, ++gent, leaf);  // zeros visible; registration complete

  if (tid == 0)
    meta[2] = __hip_atomic_load(&bar[1536 + pair], __ATOMIC_RELAXED,
                                __HIP_MEMORY_SCOPE_AGENT);
  __syncthreads();
  const unsigned nPair = meta[2];

  for (int t = 0; t < SEQ_N; ++t) {
    double* scr = scr0 + (size_t)(t & 1) * 16384;
    // ---- x & W1 loads first (L2-fast; in-order vmcnt lets x-FMA start early) ----
    float2 xv[4][4], wv[4][4];
#pragma unroll
    for (int i = 0; i < 4; ++i) {
      int c2 = i * 32 + ks;
#pragma unroll
      for (int r = 0; r < 4; ++r)
        xv[r][i] = ((const float2*)(x + ((size_t)t * 64 + g * 16 + bg * 4 + r) * 256))[c2];
#pragma unroll
      for (int jn = 0; jn < 4; ++jn)
        wv[jn][i] = ((const float2*)w1row[jn])[c2];
    }
    __builtin_amdgcn_sched_barrier(0);
    // ---- issue stage loads (my rank-strided rows of group-g v from IF$) ----
    const int r0 = (int)rank, r1 = (int)(rank + nPair);
    const bool h0 = r0 < 16, h1 = r1 < 16;
    double a0 = 0, a1 = 0, b0 = 0, b1 = 0;
    if (h0) {
      const double* s = vin + (size_t)(g * 16 + r0) * WDIM + tid * 2;
      a0 = gload(s); a1 = gload(s + 1);
    }
    if (h1) {
      const double* s = vin + (size_t)(g * 16 + r1) * WDIM + tid * 2;
      b0 = gload(s); b1 = gload(s + 1);
    }
    // ---- x-injection FMA (overlaps stage-load latency) ----
    double accx[4][4], accy[4][4];
#pragma unroll
    for (int ib = 0; ib < 4; ++ib)
#pragma unroll
      for (int jn = 0; jn < 4; ++jn) { accx[ib][jn] = 0.0; accy[ib][jn] = 0.0; }
#pragma unroll
    for (int i = 0; i < 4; ++i)
#pragma unroll
      for (int jn = 0; jn < 4; ++jn) {
        double wx = (double)wv[jn][i].x, wy = (double)wv[jn][i].y;
        accx[0][jn] += (double)xv[0][i].x * wx; accy[0][jn] += (double)xv[0][i].y * wy;
        accx[1][jn] += (double)xv[1][i].x * wx; accy[1][jn] += (double)xv[1][i].y * wy;
        accx[2][jn] += (double)xv[2][i].x * wx; accy[2][jn] += (double)xv[2][i].y * wy;
        accx[3][jn] += (double)xv[3][i].x * wx; accy[3][jn] += (double)xv[3][i].y * wy;
      }
    // ---- write staged rows to XCD-local scratch (plain stores -> dirty L2) ----
    if (h0) *(double2*)(scr + (size_t)r0 * WDIM + tid * 2) = make_double2(a0, a1);
    if (h1) *(double2*)(scr + (size_t)r1 * WDIM + tid * 2) = make_double2(b0, b1);
    for (int r = (int)(rank + 2 * nPair); r < 16; r += (int)nPair) {  // rare path
      const double* s = vin + (size_t)(g * 16 + r) * WDIM + tid * 2;
      double d0 = gload(s), d1 = gload(s + 1);
      *(double2*)(scr + (size_t)r * WDIM + tid * 2) = make_double2(d0, d1);
    }
    __syncthreads();  // drains all waves' stores (vmcnt) before flag
    if (tid == 0) {
      __hip_atomic_fetch_add(&xflag[0], 1u, __ATOMIC_RELAXED, __HIP_MEMORY_SCOPE_AGENT);
      unsigned tgt = (unsigned)(t + 1) * nPair;
      while (__hip_atomic_load(&xflag[0], __ATOMIC_RELAXED, __HIP_MEMORY_SCOPE_AGENT) < tgt)
        __builtin_amdgcn_s_sleep(1);
    }
    __syncthreads();
    asm volatile("buffer_inv" ::: "memory");  // L1-only inv: drop stale scratch lines

    // ---- consume: plain cached loads from XCD-local L2 ----
    double2 vld[16];
#pragma unroll
    for (int j = 0; j < 16; ++j)
      vld[j] = *(const double2*)(scr + (size_t)j * WDIM + tid * 2);
#pragma unroll
    for (int j = 0; j < 16; ++j)
      tile[j * 512 + tid] = vld[j];
    __syncthreads();  // S1

    // ---- weight FMA over full K ----
#pragma unroll 4
    for (int i = 0; i < 16; ++i) {
      int c2 = i * 32 + ks;
      double2 v0 = tile[(bg * 4 + 0) * 512 + c2];
      double2 v1 = tile[(bg * 4 + 1) * 512 + c2];
      double2 v2 = tile[(bg * 4 + 2) * 512 + c2];
      double2 v3 = tile[(bg * 4 + 3) * 512 + c2];
#pragma unroll
      for (int jn = 0; jn < 4; ++jn) {
        double2 w = ((const double2*)wrow[jn])[c2];
        accx[0][jn] += v0.x * w.x; accy[0][jn] += v0.y * w.y;
        accx[1][jn] += v1.x * w.x; accy[1][jn] += v1.y * w.y;
        accx[2][jn] += v2.x * w.x; accy[2][jn] += v2.y * w.y;
        accx[3][jn] += v3.x * w.x; accy[3][jn] += v3.y * w.y;
      }
    }
#pragma unroll
    for (int ib = 0; ib < 4; ++ib)
#pragma unroll
      for (int jn = 0; jn < 4; ++jn) {
        double p = accx[ib][jn] + accy[ib][jn];
        p += __shfl_xor(p, 16, 64);
        if (ks < 16) {
          int o = (bg * 4 + ib) * 16 + ng * 4 + jn;
          red[o * 16 + (ks ^ ((oswz + jn) & 15))] = p;
        }
      }
    __syncthreads();  // S2
    if (tid < 256) {
      double s = 0.0;
      const int oc = tid & 15;
#pragma unroll
      for (int slc = 0; slc < 16; ++slc)
        s += red[tid * 16 + (slc ^ oc)];
      double u = s + (t == 0 ? c0r : b1cr);
      double gv = u + bo * sin(u * inw);
      gstore(&vout[(size_t)b_red * WDIM + n_red], gv);
    }
    gbarNF(bar, ++gent, leaf);
    double* tmp = vin; vin = vout; vout = tmp;
  }

  // ---------------- epilogue: stream = v_2047 @ W2^T + b2 (direct IF$ reads) ----
  {
    double va[16], vb[16];
    {
      const double* srcb = vin + (size_t)(g * 16) * WDIM + tid * 2;
#pragma unroll
      for (int j = 0; j < 16; ++j) {
        va[j] = gload(srcb + (size_t)j * WDIM);
        vb[j] = gload(srcb + (size_t)j * WDIM + 1);
      }
    }
#pragma unroll
    for (int j = 0; j < 16; ++j)
      tile[j * 512 + tid] = make_double2(va[j], vb[j]);
    __syncthreads();
    double accx[4][4], accy[4][4];
#pragma unroll
    for (int ib = 0; ib < 4; ++ib)
#pragma unroll
      for (int jn = 0; jn < 4; ++jn) { accx[ib][jn] = 0.0; accy[ib][jn] = 0.0; }
#pragma unroll 4
    for (int i = 0; i < 16; ++i) {
      int c2 = i * 32 + ks;
      double2 v0 = tile[(bg * 4 + 0) * 512 + c2];
      double2 v1 = tile[(bg * 4 + 1) * 512 + c2];
      double2 v2 = tile[(bg * 4 + 2) * 512 + c2];
      double2 v3 = tile[(bg * 4 + 3) * 512 + c2];
#pragma unroll
      for (int jn = 0; jn < 4; ++jn) {
        float2 wf = ((const float2*)w2row[jn])[c2];
        double wx = (double)wf.x, wy = (double)wf.y;
        accx[0][jn] += v0.x * wx; accy[0][jn] += v0.y * wy;
        accx[1][jn] += v1.x * wx; accy[1][jn] += v1.y * wy;
        accx[2][jn] += v2.x * wx; accy[2][jn] += v2.y * wy;
        accx[3][jn] += v3.x * wx; accy[3][jn] += v3.y * wy;
      }
    }
#pragma unroll
    for (int ib = 0; ib < 4; ++ib)
#pragma unroll
      for (int jn = 0; jn < 4; ++jn) {
        double p = accx[ib][jn] + accy[ib][jn];
        p += __shfl_xor(p, 16, 64);
        if (ks < 16) {
          int o = (bg * 4 + ib) * 16 + ng * 4 + jn;
          red[o * 16 + (ks ^ ((oswz + jn) & 15))] = p;
        }
      }
    __syncthreads();
    if (tid < 256) {
      double s = 0.0;
      const int oc = tid & 15;
#pragma unroll
      for (int slc = 0; slc < 16; ++slc)
        s += red[tid * 16 + (slc ^ oc)];
      double sv = s + (double)b2[n_red];
      out[4096 + (size_t)b_red * WDIM + n_red] = (float)sv;
      if (n_red < 64) out[(size_t)b_red * 64 + n_red] = (float)sv;
    }
  }
}

// ================= LEGACY fallback: r6-exact (256 x 512, 160 KB) =================
__global__ __launch_bounds__(512, 2) void k_main(
    const float* __restrict__ x, const double* __restrict__ Wcd,
    const float* __restrict__ W1, const double* __restrict__ b1c,
    const double* __restrict__ c0, const float* __restrict__ W2,
    const float* __restrict__ b2, const float* __restrict__ bend,
    const float* __restrict__ inner, const float* __restrict__ outer,
    double* vA, double* vB, float* __restrict__ out, unsigned* bar) {
  extern __shared__ double2 tile[];
  double* red = (double*)(tile + 8192);
  const int tid = threadIdx.x;
  const int ks = tid & 31;
  const int bg = (tid >> 5) & 3;
  const int ng = (tid >> 7) & 3;
  const int nt = blockIdx.x & 63, g = blockIdx.x >> 6;
  const int leaf = blockIdx.x >> 4;

  if (tid < 256) vA[blockIdx.x * 256 + tid] = 0.0;

  const double* wrow[4];
  const float* w1row[4];
  const float* w2row[4];
#pragma unroll
  for (int jn = 0; jn < 4; ++jn) {
    int n = nt * 16 + ng * 4 + jn;
    wrow[jn]  = Wcd + (size_t)n * WDIM;
    w1row[jn] = W1 + (size_t)n * WDIM;
    w2row[jn] = W2 + (size_t)n * WDIM;
  }
  const int n_red = nt * 16 + (tid & 15);
  const int b_red = g * 16 + ((tid >> 4) & 15);
  const double bo   = (double)bend[n_red] * (double)outer[n_red];
  const double inw  = (double)inner[n_red];
  const double b1cr = b1c[n_red];
  const double c0r  = c0[n_red];
  const int oswz = (ng * 4) & 15;

  unsigned gent = 0;
  double* vin = vA;
  double* vout = vB;
  gbarF(bar, ++gent, leaf);

  for (int t = 0; t < SEQ_N; ++t) {
    float2 xv[4][4], wv[4][4];
#pragma unroll
    for (int i = 0; i < 4; ++i) {
      int c2 = i * 32 + ks;
#pragma unroll
      for (int r = 0; r < 4; ++r)
        xv[r][i] = ((const float2*)(x + ((size_t)t * 64 + g * 16 + bg * 4 + r) * 256))[c2];
#pragma unroll
      for (int jn = 0; jn < 4; ++jn)
        wv[jn][i] = ((const float2*)w1row[jn])[c2];
    }
    double va[16], vb[16];
    {
      const double* srcb = vin + (size_t)(g * 16) * WDIM + tid * 2;
#pragma unroll
      for (int j = 0; j < 16; ++j) {
        va[j] = gload(srcb + (size_t)j * WDIM);
        vb[j] = gload(srcb + (size_t)j * WDIM + 1);
      }
    }
    double accx[4][4], accy[4][4];
#pragma unroll
    for (int ib = 0; ib < 4; ++ib)
#pragma unroll
      for (int jn = 0; jn < 4; ++jn) { accx[ib][jn] = 0.0; accy[ib][jn] = 0.0; }
#pragma unroll
    for (int i = 0; i < 4; ++i)
#pragma unroll
      for (int jn = 0; jn < 4; ++jn) {
        double wx = (double)wv[jn][i].x, wy = (double)wv[jn][i].y;
        accx[0][jn] += (double)xv[0][i].x * wx; accy[0][jn] += (double)xv[0][i].y * wy;
        accx[1][jn] += (double)xv[1][i].x * wx; accy[1][jn] += (double)xv[1][i].y * wy;
        accx[2][jn] += (double)xv[2][i].x * wx; accy[2][jn] += (double)xv[2][i].y * wy;
        accx[3][jn] += (double)xv[3][i].x * wx; accy[3][jn] += (double)xv[3][i].y * wy;
      }
#pragma unroll
    for (int j = 0; j < 16; ++j)
      tile[j * 512 + tid] = make_double2(va[j], vb[j]);
    __syncthreads();
#pragma unroll 4
    for (int i = 0; i < 16; ++i) {
      int c2 = i * 32 + ks;
      double2 v0 = tile[(bg * 4 + 0) * 512 + c2];
      double2 v1 = tile[(bg * 4 + 1) * 512 + c2];
      double2 v2 = tile[(bg * 4 + 2) * 512 + c2];
      double2 v3 = tile[(bg * 4 + 3) * 512 + c2];
#pragma unroll
      for (int jn = 0; jn < 4; ++jn) {
        double2 w = ((const double2*)wrow[jn])[c2];
        accx[0][jn] += v0.x * w.x; accy[0][jn] += v0.y * w.y;
        accx[1][jn] += v1.x * w.x; accy[1][jn] += v1.y * w.y;
        accx[2][jn] += v2.x * w.x; accy[2][jn] += v2.y * w.y;
        accx[3][jn] += v3.x * w.x; accy[3][jn] += v3.y * w.y;
      }
    }
#pragma unroll
    for (int ib = 0; ib < 4; ++ib)
#pragma unroll
      for (int jn = 0; jn < 4; ++jn) {
        double p = accx[ib][jn] + accy[ib][jn];
        p += __shfl_xor(p, 16, 64);
        if (ks < 16) {
          int o = (bg * 4 + ib) * 16 + ng * 4 + jn;
          red[o * 16 + (ks ^ ((oswz + jn) & 15))] = p;
        }
      }
    __syncthreads();
    if (tid < 256) {
      double s = 0.0;
      const int oc = tid & 15;
#pragma unroll
      for (int slc = 0; slc < 16; ++slc)
        s += red[tid * 16 + (slc ^ oc)];
      double u = s + (t == 0 ? c0r : b1cr);
      double gv = u + bo * sin(u * inw);
      gstore(&vout[(size_t)b_red * WDIM + n_red], gv);
    }
    gbarF(bar, ++gent, leaf);
    double* tmp = vin; vin = vout; vout = tmp;
  }
  {
    double va[16], vb[16];
    {
      const double* srcb = vin + (size_t)(g * 16) * WDIM + tid * 2;
#pragma unroll
      for (int j = 0; j < 16; ++j) {
        va[j] = gload(srcb + (size_t)j * WDIM);
        vb[j] = gload(srcb + (size_t)j * WDIM + 1);
      }
    }
#pragma unroll
    for (int j = 0; j < 16; ++j)
      tile[j * 512 + tid] = make_double2(va[j], vb[j]);
    __syncthreads();
    double accx[4][4], accy[4][4];
#pragma unroll
    for (int ib = 0; ib < 4; ++ib)
#pragma unroll
      for (int jn = 0; jn < 4; ++jn) { accx[ib][jn] = 0.0; accy[ib][jn] = 0.0; }
#pragma unroll 4
    for (int i = 0; i < 16; ++i) {
      int c2 = i * 32 + ks;
      double2 v0 = tile[(bg * 4 + 0) * 512 + c2];
      double2 v1 = tile[(bg * 4 + 1) * 512 + c2];
      double2 v2 = tile[(bg * 4 + 2) * 512 + c2];
      double2 v3 = tile[(bg * 4 + 3) * 512 + c2];
#pragma unroll
      for (int jn = 0; jn < 4; ++jn) {
        float2 wf = ((const float2*)w2row[jn])[c2];
        double wx = (double)wf.x, wy = (double)wf.y;
        accx[0][jn] += v0.x * wx; accy[0][jn] += v0.y * wy;
        accx[1][jn] += v1.x * wx; accy[1][jn] += v1.y * wy;
        accx[2][jn] += v2.x * wx; accy[2][jn] += v2.y * wy;
        accx[3][jn] += v3.x * wx; accy[3][jn] += v3.y * wy;
      }
    }
#pragma unroll
    for (int ib = 0; ib < 4; ++ib)
#pragma unroll
      for (int jn = 0; jn < 4; ++jn) {
        double p = accx[ib][jn] + accy[ib][jn];
        p += __shfl_xor(p, 16, 64);
        if (ks < 16) {
          int o = (bg * 4 + ib) * 16 + ng * 4 + jn;
          red[o * 16 + (ks ^ ((oswz + jn) & 15))] = p;
        }
      }
    __syncthreads();
    if (tid < 256) {
      double s = 0.0;
      const int oc = tid & 15;
#pragma unroll
      for (int slc = 0; slc < 16; ++slc)
        s += red[tid * 16 + (slc ^ oc)];
      double sv = s + (double)b2[n_red];
      out[4096 + (size_t)b_red * WDIM + n_red] = (float)sv;
      if (n_red < 64) out[(size_t)b_red * 64 + n_red] = (float)sv;
    }
  }
}

extern "C" void kernel_launch(void* const* d_in, const int* in_sizes, int n_in,
                              void* d_out, int out_size, void* d_ws, size_t ws_size,
                              hipStream_t stream) {
  const float* x    = (const float*)d_in[0];
  const float* s0   = (const float*)d_in[1];
  const float* W1   = (const float*)d_in[2];
  const float* b1   = (const float*)d_in[3];
  const float* W2   = (const float*)d_in[4];
  const float* b2   = (const float*)d_in[5];
  const float* bend = (const float*)d_in[6];
  const float* inner= (const float*)d_in[7];
  const float* outer= (const float*)d_in[8];
  double* ws = (double*)d_ws;

  double* Wcd = ws;
  double* b1c = ws + 1048576;
  double* c0  = ws + 1049600;
  double* vA  = ws + 1050624;
  double* vB  = ws + 1116160;
  unsigned* bar = (unsigned*)(ws + 1181696);   // 4096 dwords (2048 doubles)
  double* scratch = ws + 1183744;              // 8*4*2*16384 = 1048576 doubles
  const size_t ws_needed = (size_t)(1183744 + 1048576) * 8;
  float* out = (float*)d_out;

  k_gemm_wt<<<dim3(16, 16), 256, 0, stream>>>(W1, W2, Wcd);
  k_bias<<<256, 256, 0, stream>>>(W1, b1, b2, s0, b1c, c0, bar);

  static bool attr_done = false;
  if (!attr_done) {
    hipFuncSetAttribute((const void*)k_mainX, hipFuncAttributeMaxDynamicSharedMemorySize, LDS_BYTES);
    hipFuncSetAttribute((const void*)k_main,  hipFuncAttributeMaxDynamicSharedMemorySize, LDS_BYTES);
    attr_done = true;
  }

  if (ws_size >= ws_needed) {
    void* args[] = { (void*)&x, (void*)&Wcd, (void*)&W1, (void*)&b1c, (void*)&c0,
                     (void*)&W2, (void*)&b2, (void*)&bend, (void*)&inner, (void*)&outer,
                     (void*)&vA, (void*)&vB, (void*)&scratch, (void*)&out, (void*)&bar };
    if (hipLaunchCooperativeKernel((void*)k_mainX, dim3(NB), dim3(512), args,
                                   LDS_BYTES, stream) != hipSuccess)
      k_mainX<<<dim3(NB), dim3(512), LDS_BYTES, stream>>>(
          x, Wcd, W1, b1c, c0, W2, b2, bend, inner, outer, vA, vB, scratch, out, bar);
  } else {
    void* args[] = { (void*)&x, (void*)&Wcd, (void*)&W1, (void*)&b1c, (void*)&c0,
                     (void*)&W2, (void*)&b2, (void*)&bend, (void*)&inner, (void*)&outer,
                     (void*)&vA, (void*)&vB, (void*)&out, (void*)&bar };
    if (hipLaunchCooperativeKernel((void*)k_main, dim3(NB), dim3(512), args,
                                   LDS_BYTES, stream) != hipSuccess)
      k_main<<<dim3(NB), dim3(512), LDS_BYTES, stream>>>(
          x, Wcd, W1, b1c, c0, W2, b2, bend, inner, outer, vA, vB, out, bar);
  }
}